// Round 3
// baseline (105.475 us; speedup 1.0000x reference)
//
#include <hip/hip_runtime.h>

// VQ nearest-codebook: x [16,64,64,64] NCHW fp32, emb [512,64] fp32.
// out = concat(one_hot [65536,512] f32, quantized [16,64,64,64] f32).
//
// Round-3 structure:
//   prep kernel: emb -> bf16 hi/lo split arrays + e_sq in d_ws (L2-resident).
//   main kernel: barrier-free. Per wave (16 pixels):
//     issue one-hot ZERO stores first (overlaps everything),
//     A-frags from global x, B-frags from global bf16 codebook (L2),
//     3-pass split-bf16 MFMA -> fp32 scores, in-reg top-2, fp64 tie refine,
//     vmcnt(0), scatter 1.0s, quant writes.

constexpr int D   = 64;
constexpr int K   = 512;
constexpr int N   = 65536;
constexpr int HW  = 4096;
constexpr int TPB = 256;
constexpr int PIX = 64;                    // pixels per block (16 per wave)
constexpr int NTILE = K / 16;              // 32 MFMA code tiles

typedef __attribute__((ext_vector_type(8))) short bf16x8;
typedef __attribute__((ext_vector_type(4))) short short4v;
typedef __attribute__((ext_vector_type(4))) float f32x4;

__device__ inline unsigned short f2bf(float f) {           // RNE f32->bf16
    unsigned u = __builtin_bit_cast(unsigned, f);
    unsigned r = u + 0x7fffu + ((u >> 16) & 1u);
    return (unsigned short)(r >> 16);
}
__device__ inline float bf2f(unsigned short h) {
    unsigned u = ((unsigned)h) << 16;
    return __builtin_bit_cast(float, u);
}

// ---------------- prep: codebook -> hi/lo bf16 + e_sq ----------------
__global__ __launch_bounds__(TPB) void vq_prep(
    const float* __restrict__ emb, short* __restrict__ ebf_hi,
    short* __restrict__ ebf_lo, float* __restrict__ esq)
{
    const int t   = blockIdx.x * TPB + threadIdx.x;   // 8192 threads
    const int row = t >> 4;
    const int q   = t & 15;
    float4 f = ((const float4*)emb)[t];
    unsigned short h0 = f2bf(f.x), h1 = f2bf(f.y), h2 = f2bf(f.z), h3 = f2bf(f.w);
    short4v hv = { (short)h0, (short)h1, (short)h2, (short)h3 };
    short4v lv = { (short)f2bf(f.x - bf2f(h0)), (short)f2bf(f.y - bf2f(h1)),
                   (short)f2bf(f.z - bf2f(h2)), (short)f2bf(f.w - bf2f(h3)) };
    *(short4v*)&ebf_hi[row * D + q * 4] = hv;
    *(short4v*)&ebf_lo[row * D + q * 4] = lv;
    float pe = f.x * f.x + f.y * f.y + f.z * f.z + f.w * f.w;
    pe += __shfl_xor(pe, 1);
    pe += __shfl_xor(pe, 2);
    pe += __shfl_xor(pe, 4);
    pe += __shfl_xor(pe, 8);
    if (q == 0) esq[row] = pe;
}

// ---------------- main ----------------
__global__ __launch_bounds__(TPB, 6) void vq_main(
    const float* __restrict__ x, const float* __restrict__ emb,
    const short* __restrict__ ebf_hi, const short* __restrict__ ebf_lo,
    const float* __restrict__ esq,
    float* __restrict__ enc, float* __restrict__ quant)
{
    __shared__ float s_bs[4][16], s_ss[4][16];
    __shared__ int   s_bi[4][16], s_si[4][16], s_idx[4][16];

    const int tid  = threadIdx.x;
    const int lane = tid & 63;
    const int wave = __builtin_amdgcn_readfirstlane(tid >> 6);
    const int g    = lane >> 4;        // k-slice group
    const int cl   = lane & 15;        // entity column in MFMA tile

    const int pixbase = blockIdx.x * PIX;
    const int b    = pixbase >> 12;
    const int hw0  = pixbase & (HW - 1);
    const int wpix = hw0 + wave * 16;                 // wave's 16 pixels in plane b
    const float* xb = x + (size_t)b * D * HW;

    // ---- 1) per-lane x loads issued FIRST (16 dwords, 64B-coalesced per group) ----
    float xv[16];
    #pragma unroll
    for (int j = 0; j < 8; ++j) {
        xv[j]     = xb[(size_t)(g * 8 + j) * HW + wpix + cl];
        xv[8 + j] = xb[(size_t)(32 + g * 8 + j) * HW + wpix + cl];
    }

    // ---- 2) one-hot ZERO stores: wave's 16 rows = 2048 float4, fire-and-forget ----
    {
        float4 z = {0.f, 0.f, 0.f, 0.f};
        float4* encw = (float4*)(enc + (size_t)(pixbase + wave * 16) * K);
        #pragma unroll
        for (int i = 0; i < 32; ++i) encw[i * 64 + lane] = z;
    }

    // ---- 3) pack A fragments hi/lo (waits on x loads only; stores stay in flight) ----
    bf16x8 ah0, ah1, al0, al1;
    #pragma unroll
    for (int j = 0; j < 8; ++j) {
        unsigned short h0 = f2bf(xv[j]);
        unsigned short h1 = f2bf(xv[8 + j]);
        ah0[j] = (short)h0;                       al0[j] = (short)f2bf(xv[j]     - bf2f(h0));
        ah1[j] = (short)h1;                       al1[j] = (short)f2bf(xv[8 + j] - bf2f(h1));
    }

    // ---- 4) 32 code tiles: B frags straight from L2-resident bf16 codebook ----
    float bs[4], ss[4];
    int   bi[4], si[4];
    #pragma unroll
    for (int r = 0; r < 4; ++r) { bs[r] = 3.4e38f; ss[r] = 3.4e38f; bi[r] = 0x7fffffff; si[r] = 0x7fffffff; }

    #pragma unroll 2
    for (int ct = 0; ct < NTILE; ++ct) {
        const int code = ct * 16 + cl;
        const short* bh = ebf_hi + (size_t)code * D;
        const short* bl = ebf_lo + (size_t)code * D;
        bf16x8 bh0 = *(const bf16x8*)(bh + g * 8);
        bf16x8 bh1 = *(const bf16x8*)(bh + 32 + g * 8);
        bf16x8 bl0 = *(const bf16x8*)(bl + g * 8);
        bf16x8 bl1 = *(const bf16x8*)(bl + 32 + g * 8);
        f32x4 c = {0.f, 0.f, 0.f, 0.f};
        c = __builtin_amdgcn_mfma_f32_16x16x32_bf16(ah0, bh0, c, 0, 0, 0);
        c = __builtin_amdgcn_mfma_f32_16x16x32_bf16(ah1, bh1, c, 0, 0, 0);
        c = __builtin_amdgcn_mfma_f32_16x16x32_bf16(ah0, bl0, c, 0, 0, 0);
        c = __builtin_amdgcn_mfma_f32_16x16x32_bf16(ah1, bl1, c, 0, 0, 0);
        c = __builtin_amdgcn_mfma_f32_16x16x32_bf16(al0, bh0, c, 0, 0, 0);
        c = __builtin_amdgcn_mfma_f32_16x16x32_bf16(al1, bh1, c, 0, 0, 0);
        const float eq = esq[code];
        #pragma unroll
        for (int r = 0; r < 4; ++r) {
            float s = fmaf(-2.0f, c[r], eq);      // x_sq dropped (row-constant)
            bool c1 = s < bs[r];
            bool c2 = s < ss[r];
            ss[r] = c1 ? bs[r] : (c2 ? s : ss[r]);
            si[r] = c1 ? bi[r] : (c2 ? code : si[r]);
            bs[r] = c1 ? s : bs[r];
            bi[r] = c1 ? code : bi[r];
        }
    }

    // ---- 5) cross-lane top-2 merge (16 lanes of each g-group share 4 pixel rows) ----
    #pragma unroll
    for (int r = 0; r < 4; ++r) {
        for (int m = 1; m <= 8; m <<= 1) {
            float obs = __shfl_xor(bs[r], m); int obi = __shfl_xor(bi[r], m);
            float oss = __shfl_xor(ss[r], m); int osi = __shfl_xor(si[r], m);
            {
                bool c1 = (obs < bs[r]) || (obs == bs[r] && obi < bi[r]);
                bool c2 = (obs < ss[r]) || (obs == ss[r] && obi < si[r]);
                ss[r] = c1 ? bs[r] : (c2 ? obs : ss[r]);
                si[r] = c1 ? bi[r] : (c2 ? obi : si[r]);
                bs[r] = c1 ? obs : bs[r];
                bi[r] = c1 ? obi : bi[r];
            }
            {
                bool c1 = (oss < bs[r]) || (oss == bs[r] && osi < bi[r]);
                bool c2 = (oss < ss[r]) || (oss == ss[r] && osi < si[r]);
                ss[r] = c1 ? bs[r] : (c2 ? oss : ss[r]);
                si[r] = c1 ? bi[r] : (c2 ? osi : si[r]);
                bs[r] = c1 ? oss : bs[r];
                bi[r] = c1 ? osi : bi[r];
            }
        }
    }
    if (cl == 0) {
        #pragma unroll
        for (int r = 0; r < 4; ++r) {
            const int p = g * 4 + r;              // C/D row within wave's 16 pixels
            s_bs[wave][p] = bs[r];  s_ss[wave][p] = ss[r];
            s_bi[wave][p] = bi[r];  s_si[wave][p] = si[r];
        }
    }
    // wave-internal LDS RAW: compiler orders via lgkmcnt; no barrier needed.

    // ---- 6) fp64 refinement of near-ties (lane cl handles pixel cl of this wave) ----
    if (cl == lane) {                             // lanes 0..15
        int fin = s_bi[wave][cl];
        if (s_ss[wave][cl] - s_bs[wave][cl] < 0.125f) {
            const int i0 = fin, i1 = s_si[wave][cl];
            const float* xq = xb + wpix + cl;
            const float* e0 = emb + (size_t)i0 * D;
            const float* e1 = emb + (size_t)i1 * D;
            double s0 = 0.0, s1 = 0.0;
            for (int d = 0; d < D; ++d) {
                double xvv = (double)xq[(size_t)d * HW];
                double ev0 = (double)e0[d];
                double ev1 = (double)e1[d];
                s0 += ev0 * (ev0 - 2.0 * xvv);
                s1 += ev1 * (ev1 - 2.0 * xvv);
            }
            if (s1 < s0 || (s1 == s0 && i1 < i0)) fin = i1;
        }
        s_idx[wave][cl] = fin;
    }

    // ---- 7) wait zero-stores retired (long done), then scatter the 1.0s ----
    asm volatile("s_waitcnt vmcnt(0)" ::: "memory");
    if (lane < 16)
        enc[(size_t)(pixbase + wave * 16 + lane) * K + s_idx[wave][lane]] = 1.0f;

    // ---- 8) quant write: lane = (c0,p16); coalesced 64B segments ----
    {
        const int p16 = lane & 15;
        const int c0  = lane >> 4;
        const int id  = s_idx[wave][p16];
        float* qb = quant + (size_t)b * D * HW + wpix + p16;
        #pragma unroll
        for (int j = 0; j < 16; ++j) {
            int ch = c0 * 16 + j;
            qb[(size_t)ch * HW] = emb[(size_t)id * D + ch];
        }
    }
}

extern "C" void kernel_launch(void* const* d_in, const int* in_sizes, int n_in,
                              void* d_out, int out_size, void* d_ws, size_t ws_size,
                              hipStream_t stream)
{
    const float* x   = (const float*)d_in[0];
    const float* emb = (const float*)d_in[1];
    float* enc   = (float*)d_out;
    float* quant = (float*)d_out + (size_t)N * K;

    short* ebf_hi = (short*)d_ws;
    short* ebf_lo = ebf_hi + K * D;
    float* esq    = (float*)(ebf_lo + K * D);

    hipLaunchKernelGGL(vq_prep, dim3(K * D / 4 / TPB), dim3(TPB), 0, stream,
                       emb, ebf_hi, ebf_lo, esq);
    hipLaunchKernelGGL(vq_main, dim3(N / PIX), dim3(TPB), 0, stream,
                       x, emb, ebf_hi, ebf_lo, esq, enc, quant);
}

// Round 4
// 57.603 us; speedup vs baseline: 1.8311x; 1.8311x over previous
//
#include <hip/hip_runtime.h>

// VQ nearest-codebook: x [16,64,64,64] NCHW fp32, emb [512,64] fp32.
// out = concat(one_hot [65536,512] f32, quantized [16,64,64,64] f32).
//
// Round-4 structure:
//   prep: emb -> hi/lo bf16 split, laid out in EXACT MFMA-fragment order
//         [chunk][sec:hi0,hi1,lo0,lo1][tile][cl][g][8 bf16] + e_sq. (130 KB ws)
//   main: per chunk (128 codes): linear 32 KB copy to LDS (coalesced, no
//         conversion), B-frags via contiguous ds_read_b128; each wave owns
//         32 pixels (two A-tiles) -> 12 MFMA per 4 ds_reads; fp32 top-2;
//         fp64 tie refine; then quant gathers+stores, then 128 MB one-hot
//         stream (stores last => no load waits behind store retirement).

constexpr int D    = 64;
constexpr int K    = 512;
constexpr int N    = 65536;
constexpr int HW   = 4096;
constexpr int TPB  = 256;
constexpr int PIXB = 128;            // pixels per block (32 per wave)
constexpr int NCHUNK = 4;            // 128 codes per chunk
constexpr int TPC    = 8;            // 16-code tiles per chunk

typedef __attribute__((ext_vector_type(8))) short bf16x8;
typedef __attribute__((ext_vector_type(4))) short short4v;
typedef __attribute__((ext_vector_type(4))) float f32x4;

__device__ inline unsigned short f2bf(float f) {           // RNE f32->bf16
    unsigned u = __builtin_bit_cast(unsigned, f);
    unsigned r = u + 0x7fffu + ((u >> 16) & 1u);
    return (unsigned short)(r >> 16);
}
__device__ inline float bf2f(unsigned short h) {
    unsigned u = ((unsigned)h) << 16;
    return __builtin_bit_cast(float, u);
}

__device__ inline void top2_upd(float s, int code, float& bs, float& ss, int& bi, int& si) {
    bool c1 = s < bs;
    bool c2 = s < ss;
    ss = c1 ? bs : (c2 ? s : ss);
    si = c1 ? bi : (c2 ? code : si);
    bs = c1 ? s : bs;
    bi = c1 ? code : bi;
}
__device__ inline void top2_ins(float os, int oi, float& bs, float& ss, int& bi, int& si) {
    bool c1 = (os < bs) || (os == bs && oi < bi);
    bool c2 = (os < ss) || (os == ss && oi < si);
    ss = c1 ? bs : (c2 ? os : ss);
    si = c1 ? bi : (c2 ? oi : si);
    bs = c1 ? os : bs;
    bi = c1 ? oi : bi;
}

// ---------------- prep: emb -> frag-ordered hi/lo bf16 + e_sq ----------------
// ebuf layout (shorts): chunk*16384 + sec*4096 + tile*512 + cl*32 + g*8 + j
//   sec: 0=hi dims 0..31, 1=hi dims 32..63, 2=lo dims 0..31, 3=lo dims 32..63
__global__ __launch_bounds__(TPB) void vq_prep(
    const float* __restrict__ emb, short* __restrict__ ebuf, float* __restrict__ esq)
{
    const int t    = blockIdx.x * TPB + threadIdx.x;   // 8192 threads
    const int code = t >> 4;
    const int q    = t & 15;
    const int d0   = q * 4;
    float4 f = ((const float4*)emb)[t];
    unsigned short h0 = f2bf(f.x), h1 = f2bf(f.y), h2 = f2bf(f.z), h3 = f2bf(f.w);
    short4v hv = { (short)h0, (short)h1, (short)h2, (short)h3 };
    short4v lv = { (short)f2bf(f.x - bf2f(h0)), (short)f2bf(f.y - bf2f(h1)),
                   (short)f2bf(f.z - bf2f(h2)), (short)f2bf(f.w - bf2f(h3)) };
    const int chunk = code >> 7, cc = code & 127, tile = cc >> 4, cl = cc & 15;
    const int g = (d0 >> 3) & 3, j0 = d0 & 7, secH = (d0 >= 32) ? 1 : 0;
    const int base = chunk * 16384 + tile * 512 + cl * 32 + g * 8 + j0;
    *(short4v*)&ebuf[base + secH * 4096]       = hv;
    *(short4v*)&ebuf[base + (2 + secH) * 4096] = lv;
    float pe = f.x * f.x + f.y * f.y + f.z * f.z + f.w * f.w;
    pe += __shfl_xor(pe, 1);
    pe += __shfl_xor(pe, 2);
    pe += __shfl_xor(pe, 4);
    pe += __shfl_xor(pe, 8);
    if (q == 0) esq[code] = pe;
}

// ---------------- main ----------------
__global__ __launch_bounds__(TPB, 2) void vq_main(
    const float* __restrict__ x, const float* __restrict__ emb,
    const short* __restrict__ ebuf, const float* __restrict__ esq,
    float* __restrict__ enc, float* __restrict__ quant)
{
    __shared__ bf16x8 s_e4[2048];                 // 32 KB chunk buffer
    __shared__ float  s_bs[PIXB], s_ss[PIXB];
    __shared__ int    s_bi[PIXB], s_si[PIXB], s_idx[PIXB];

    const int tid  = threadIdx.x;
    const int lane = tid & 63;
    const int wave = __builtin_amdgcn_readfirstlane(tid >> 6);
    const int g    = lane >> 4;
    const int cl   = lane & 15;

    const int pixbase = blockIdx.x * PIXB;
    const int b    = pixbase >> 12;
    const int hw0  = pixbase & (HW - 1);
    const int wloc = wave * 32;                    // wave's pixels, block-local
    const float* xb = x + (size_t)b * D * HW;

    // ---- x loads for two A-tiles (issued first; coalesced 64B segments) ----
    float xv0[16], xv1[16];
    #pragma unroll
    for (int j = 0; j < 8; ++j) {
        const size_t o0 = (size_t)(g * 8 + j) * HW + hw0 + wloc + cl;
        const size_t o1 = (size_t)(32 + g * 8 + j) * HW + hw0 + wloc + cl;
        xv0[j]     = xb[o0];       xv0[8 + j] = xb[o1];
        xv1[j]     = xb[o0 + 16];  xv1[8 + j] = xb[o1 + 16];
    }

    // ---- pack A fragments hi/lo ----
    bf16x8 a0h0, a0h1, a0l0, a0l1, a1h0, a1h1, a1l0, a1l1;
    #pragma unroll
    for (int j = 0; j < 8; ++j) {
        unsigned short h;
        h = f2bf(xv0[j]);     a0h0[j] = (short)h; a0l0[j] = (short)f2bf(xv0[j]     - bf2f(h));
        h = f2bf(xv0[8 + j]); a0h1[j] = (short)h; a0l1[j] = (short)f2bf(xv0[8 + j] - bf2f(h));
        h = f2bf(xv1[j]);     a1h0[j] = (short)h; a1l0[j] = (short)f2bf(xv1[j]     - bf2f(h));
        h = f2bf(xv1[8 + j]); a1h1[j] = (short)h; a1l1[j] = (short)f2bf(xv1[8 + j] - bf2f(h));
    }

    float bs0[4], ss0[4], bs1[4], ss1[4];
    int   bi0[4], si0[4], bi1[4], si1[4];
    #pragma unroll
    for (int r = 0; r < 4; ++r) {
        bs0[r] = ss0[r] = bs1[r] = ss1[r] = 3.4e38f;
        bi0[r] = si0[r] = bi1[r] = si1[r] = 0x7fffffff;
    }

    const bf16x8* gsrc  = (const bf16x8*)ebuf;
    const short*  se    = (const short*)s_e4;

    for (int chunk = 0; chunk < NCHUNK; ++chunk) {
        if (chunk > 0) __syncthreads();            // prev compute done before overwrite

        // ---- linear 32 KB stage: coalesced global b128 -> conflict-free ds_write_b128 ----
        #pragma unroll
        for (int i = 0; i < 8; ++i)
            s_e4[i * 256 + tid] = gsrc[chunk * 2048 + i * 256 + tid];

        // per-wave esq prefetch for this chunk (16 dwords x 8 tiles, L1-hot)
        float eqc[TPC];
        #pragma unroll
        for (int t = 0; t < TPC; ++t) eqc[t] = esq[chunk * 128 + t * 16 + cl];

        __syncthreads();

        #pragma unroll
        for (int t = 0; t < TPC; ++t) {
            // wave-contiguous 1KB ds_read_b128 per fragment section
            const int fo = t * 512 + cl * 32 + g * 8;
            bf16x8 bh0 = *(const bf16x8*)&se[fo];
            bf16x8 bh1 = *(const bf16x8*)&se[fo + 4096];
            bf16x8 bl0 = *(const bf16x8*)&se[fo + 8192];
            bf16x8 bl1 = *(const bf16x8*)&se[fo + 12288];
            f32x4 c0 = {0.f, 0.f, 0.f, 0.f};
            f32x4 c1 = {0.f, 0.f, 0.f, 0.f};
            c0 = __builtin_amdgcn_mfma_f32_16x16x32_bf16(a0h0, bh0, c0, 0, 0, 0);
            c1 = __builtin_amdgcn_mfma_f32_16x16x32_bf16(a1h0, bh0, c1, 0, 0, 0);
            c0 = __builtin_amdgcn_mfma_f32_16x16x32_bf16(a0h1, bh1, c0, 0, 0, 0);
            c1 = __builtin_amdgcn_mfma_f32_16x16x32_bf16(a1h1, bh1, c1, 0, 0, 0);
            c0 = __builtin_amdgcn_mfma_f32_16x16x32_bf16(a0l0, bh0, c0, 0, 0, 0);
            c1 = __builtin_amdgcn_mfma_f32_16x16x32_bf16(a1l0, bh0, c1, 0, 0, 0);
            c0 = __builtin_amdgcn_mfma_f32_16x16x32_bf16(a0l1, bh1, c0, 0, 0, 0);
            c1 = __builtin_amdgcn_mfma_f32_16x16x32_bf16(a1l1, bh1, c1, 0, 0, 0);
            c0 = __builtin_amdgcn_mfma_f32_16x16x32_bf16(a0h0, bl0, c0, 0, 0, 0);
            c1 = __builtin_amdgcn_mfma_f32_16x16x32_bf16(a1h0, bl0, c1, 0, 0, 0);
            c0 = __builtin_amdgcn_mfma_f32_16x16x32_bf16(a0h1, bl1, c0, 0, 0, 0);
            c1 = __builtin_amdgcn_mfma_f32_16x16x32_bf16(a1h1, bl1, c1, 0, 0, 0);
            const int kcode = chunk * 128 + t * 16 + cl;
            #pragma unroll
            for (int r = 0; r < 4; ++r) {
                top2_upd(fmaf(-2.0f, c0[r], eqc[t]), kcode, bs0[r], ss0[r], bi0[r], si0[r]);
                top2_upd(fmaf(-2.0f, c1[r], eqc[t]), kcode, bs1[r], ss1[r], bi1[r], si1[r]);
            }
        }
    }

    // ---- cross-lane top-2 merge (over cl within each g-group) ----
    #pragma unroll
    for (int r = 0; r < 4; ++r) {
        for (int m = 1; m <= 8; m <<= 1) {
            float obs, oss; int obi, osi;
            obs = __shfl_xor(bs0[r], m); obi = __shfl_xor(bi0[r], m);
            oss = __shfl_xor(ss0[r], m); osi = __shfl_xor(si0[r], m);
            top2_ins(obs, obi, bs0[r], ss0[r], bi0[r], si0[r]);
            top2_ins(oss, osi, bs0[r], ss0[r], bi0[r], si0[r]);
            obs = __shfl_xor(bs1[r], m); obi = __shfl_xor(bi1[r], m);
            oss = __shfl_xor(ss1[r], m); osi = __shfl_xor(si1[r], m);
            top2_ins(obs, obi, bs1[r], ss1[r], bi1[r], si1[r]);
            top2_ins(oss, osi, bs1[r], ss1[r], bi1[r], si1[r]);
        }
    }
    if (cl == 0) {
        #pragma unroll
        for (int r = 0; r < 4; ++r) {
            const int p0 = wloc + g * 4 + r;          // C/D row = (lane>>4)*4+reg
            s_bs[p0] = bs0[r]; s_ss[p0] = ss0[r]; s_bi[p0] = bi0[r]; s_si[p0] = si0[r];
            const int p1 = p0 + 16;
            s_bs[p1] = bs1[r]; s_ss[p1] = ss1[r]; s_bi[p1] = bi1[r]; s_si[p1] = si1[r];
        }
    }
    __syncthreads();

    // ---- fp64 refinement of near-ties (exact argmin; error of split-bf16 ~1e-3) ----
    if (tid < PIXB) {
        int fin = s_bi[tid];
        if (s_ss[tid] - s_bs[tid] < 0.125f) {
            const int i0 = fin, i1 = s_si[tid];
            const float* xq = xb + hw0 + tid;
            const float* e0 = emb + (size_t)i0 * D;
            const float* e1 = emb + (size_t)i1 * D;
            double sa = 0.0, sb = 0.0;
            for (int d = 0; d < D; ++d) {
                double xvv = (double)xq[(size_t)d * HW];
                double ev0 = (double)e0[d];
                double ev1 = (double)e1[d];
                sa += ev0 * (ev0 - 2.0 * xvv);
                sb += ev1 * (ev1 - 2.0 * xvv);
            }
            if (sb < sa || (sb == sa && i1 < i0)) fin = i1;
        }
        s_idx[tid] = fin;
    }
    __syncthreads();

    // ---- quant FIRST (its gather loads must not queue behind the one-hot stream) ----
    {
        const int p   = tid & 127;
        const int ch0 = (tid >> 7) * 32;
        const int id  = s_idx[p];
        const float* ev = emb + (size_t)id * D;
        float* qb = quant + (size_t)b * D * HW + hw0 + p;
        #pragma unroll
        for (int j = 0; j < 32; ++j)
            qb[(size_t)(ch0 + j) * HW] = ev[ch0 + j];
    }

    // ---- one-hot full rows: branchless compare-select, coalesced float4 ----
    {
        float4* encb = (float4*)(enc + (size_t)pixbase * K);
        #pragma unroll 4
        for (int it = 0; it < (PIXB * K / 4) / TPB; ++it) {   // 64 iters
            const int e4  = it * TPB + tid;
            const int row = e4 >> 7;
            const int kk  = (e4 & 127) << 2;
            const int id  = s_idx[row];
            float4 v;
            v.x = (id == kk + 0) ? 1.0f : 0.0f;
            v.y = (id == kk + 1) ? 1.0f : 0.0f;
            v.z = (id == kk + 2) ? 1.0f : 0.0f;
            v.w = (id == kk + 3) ? 1.0f : 0.0f;
            encb[e4] = v;
        }
    }
}

extern "C" void kernel_launch(void* const* d_in, const int* in_sizes, int n_in,
                              void* d_out, int out_size, void* d_ws, size_t ws_size,
                              hipStream_t stream)
{
    const float* x   = (const float*)d_in[0];
    const float* emb = (const float*)d_in[1];
    float* enc   = (float*)d_out;
    float* quant = (float*)d_out + (size_t)N * K;

    short* ebuf = (short*)d_ws;                  // 128 KB frag-ordered hi/lo
    float* esq  = (float*)(ebuf + (size_t)K * D * 2);   // 2 KB

    hipLaunchKernelGGL(vq_prep, dim3(K * D / 4 / TPB), dim3(TPB), 0, stream,
                       emb, ebuf, esq);
    hipLaunchKernelGGL(vq_main, dim3(N / PIXB), dim3(TPB), 0, stream,
                       x, emb, ebuf, esq, enc, quant);
}